// Round 1
// baseline (137.190 us; speedup 1.0000x reference)
//
#include <hip/hip_runtime.h>
#include <hip/hip_bf16.h>
#include <stdint.h>

// ---------------- problem constants ----------------
#define B_  4
#define N_  2048
#define C_  1024
#define E_  8
#define H_  512      // C/2

typedef __bf16 bf16x8 __attribute__((ext_vector_type(8)));
typedef __bf16 bf16x4 __attribute__((ext_vector_type(4)));
typedef float  f32x4  __attribute__((ext_vector_type(4)));

// ---------------- workspace layout (bytes) ----------------
// Wb  bf16 [4][1024][1024]            :  8 MiB
// Xb  bf16 [2][4][2048][1024]         : 32 MiB   (x then x_ir)
// gx  f32  [4][1024]
// g   f32  [4][8]
// bb  f32  [4][1024]
// h   f32  [4][512]
#define WB_OFF   0ull
#define XB_OFF   (8ull*1024*1024)
#define GX_OFF   (XB_OFF + 32ull*1024*1024)
#define G_OFF    (GX_OFF + 4096ull*4)
#define BB_OFF   (G_OFF + 128ull)
#define H_OFF    (BB_OFF + 4096ull*4)

__device__ __forceinline__ void gload16(const void* g, void* l) {
  __builtin_amdgcn_global_load_lds((const __attribute__((address_space(1))) void*)g,
                                   (__attribute__((address_space(3))) void*)l, 16, 0, 0);
}

// ---------------- 1. f32 -> bf16 cast (vectorized, 8 elems/thread) ----------------
__global__ void cast_kernel(const float* __restrict__ src, __bf16* __restrict__ dst) {
  size_t i = (size_t)blockIdx.x * blockDim.x + threadIdx.x;   // one per 8 elems
  const float4* s = (const float4*)src + i * 2;
  float4 a = s[0], b = s[1];
  bf16x8 o;
  o[0] = (__bf16)a.x; o[1] = (__bf16)a.y; o[2] = (__bf16)a.z; o[3] = (__bf16)a.w;
  o[4] = (__bf16)b.x; o[5] = (__bf16)b.y; o[6] = (__bf16)b.z; o[7] = (__bf16)b.w;
  *(bf16x8*)(dst + i * 8) = o;
}

// ---------------- 2. gx = mean over N ----------------
// grid (32, 4, 4) = (n-split, c-split, b); block 256
__global__ void mean_kernel(const float* __restrict__ x, float* __restrict__ gx) {
  int b = blockIdx.z, cs = blockIdx.y, ns = blockIdx.x;
  int c = cs * 256 + threadIdx.x;
  const float* p = x + ((size_t)b * N_ + (size_t)ns * 64) * C_ + c;
  float s = 0.f;
  #pragma unroll 8
  for (int n = 0; n < 64; ++n) s += p[(size_t)n * C_];
  atomicAdd(&gx[b * C_ + c], s * (1.0f / N_));
}

// ---------------- 3. h = relu(gx @ gw1^T + gb1) ----------------
// grid 8, block 256: thread -> (b = t&3, j = blk*64 + t>>2)
__global__ void h_kernel(const float* __restrict__ gx, const float* __restrict__ gw1,
                         const float* __restrict__ gb1, float* __restrict__ h) {
  __shared__ float sgx[B_][C_];
  int t = threadIdx.x;
  for (int i = t; i < B_ * C_; i += 256) sgx[i >> 10][i & 1023] = gx[i];
  __syncthreads();
  int j = blockIdx.x * 64 + (t >> 2);
  int b = t & 3;
  const float4* row = (const float4*)(gw1 + (size_t)j * C_);
  float acc = 0.f;
  #pragma unroll 4
  for (int c4 = 0; c4 < C_ / 4; ++c4) {
    float4 w = row[c4];
    acc += w.x * sgx[b][c4*4+0] + w.y * sgx[b][c4*4+1]
         + w.z * sgx[b][c4*4+2] + w.w * sgx[b][c4*4+3];
  }
  h[b * H_ + j] = fmaxf(acc + gb1[j], 0.f);
}

// ---------------- 4. logits + softmax -> g ----------------
// 1 block, 512 threads (8 waves); each wave does 4 (b,e) dot-512 reductions
__global__ __launch_bounds__(512) void gate2_kernel(const float* __restrict__ h,
    const float* __restrict__ gw2, const float* __restrict__ gb2, float* __restrict__ g) {
  __shared__ float slog[B_ * E_];
  int t = threadIdx.x, wv = t >> 6, lane = t & 63;
  for (int q = 0; q < 4; ++q) {
    int pi = wv * 4 + q;          // 0..31
    int b = pi >> 3, e = pi & 7;
    float s = 0.f;
    for (int k = lane; k < H_; k += 64) s += h[b * H_ + k] * gw2[e * H_ + k];
    for (int off = 32; off; off >>= 1) s += __shfl_down(s, off);
    if (lane == 0) slog[pi] = s + gb2[e];
  }
  __syncthreads();
  if (t < B_) {
    float m = -1e30f;
    for (int e = 0; e < E_; ++e) m = fmaxf(m, slog[t * E_ + e]);
    float p[E_], sum = 0.f;
    for (int e = 0; e < E_; ++e) { p[e] = __expf(slog[t * E_ + e] - m); sum += p[e]; }
    float inv = 1.f / sum;
    for (int e = 0; e < E_; ++e) g[t * E_ + e] = p[e] * inv;
  }
}

// ---------------- 5. bb = g @ be ----------------
__global__ void bb_kernel(const float* __restrict__ g, const float* __restrict__ be,
                          float* __restrict__ bb) {
  int i = blockIdx.x * 256 + threadIdx.x;   // 0..4095
  int b = i >> 10, o = i & 1023;
  float s = 0.f;
  #pragma unroll
  for (int e = 0; e < E_; ++e) s += g[b * E_ + e] * be[e * C_ + o];
  bb[i] = s;
}

// ---------------- 6. Wb[b] = sum_e g[b,e]*We[e]  (bf16 out) ----------------
// grid 4096, block 256: thread handles 4 consecutive c's (float4 loads)
__global__ void wb_kernel(const float* __restrict__ g, const float* __restrict__ We,
                          __bf16* __restrict__ Wb) {
  size_t i = (size_t)blockIdx.x * 256 + threadIdx.x;   // 0 .. 2^20-1
  int b = (int)(i >> 18);
  size_t oc4 = i & ((1u << 18) - 1);                    // o*256 + c4
  float gl[E_];
  #pragma unroll
  for (int e = 0; e < E_; ++e) gl[e] = g[b * E_ + e];
  const float4* src = (const float4*)We + oc4;
  float4 acc = make_float4(0.f, 0.f, 0.f, 0.f);
  #pragma unroll
  for (int e = 0; e < E_; ++e) {
    float4 w = src[(size_t)e * (C_ * C_ / 4)];
    acc.x += gl[e] * w.x; acc.y += gl[e] * w.y;
    acc.z += gl[e] * w.z; acc.w += gl[e] * w.w;
  }
  bf16x4 o;
  o[0] = (__bf16)acc.x; o[1] = (__bf16)acc.y; o[2] = (__bf16)acc.z; o[3] = (__bf16)acc.w;
  *(bf16x4*)(Wb + i * 4) = o;
}

// ---------------- 7. batched GEMM: out = Xb @ Wb^T + bb ----------------
// m97 structure: 128x128 tile, BK=32, 4 waves, each wave 64x64 (4x4 frags of 16x16)
#define BM 128
#define BN 128
#define BK 32

__global__ __launch_bounds__(256) void moe_gemm(const __bf16* __restrict__ Xb,
    const __bf16* __restrict__ Wb, const float* __restrict__ bb, float* __restrict__ out) {
  __shared__ __bf16 As[BM * BK];   // 8 KiB, linear [128][32]
  __shared__ __bf16 Bs[BN * BK];

  const int t = threadIdx.x;
  const int z = blockIdx.z, b = z & 3;     // src = z >> 2 folded into base offsets
  const size_t mat = (size_t)N_ * C_;
  const __bf16* A  = Xb + (size_t)z * mat;       // [src][b] contiguous
  const __bf16* Bm = Wb + (size_t)b * C_ * C_;
  float* O = out + (size_t)z * mat;

  const int row0 = blockIdx.y * BM;
  const int col0 = blockIdx.x * BN;

  const int trow = t >> 2;            // 0..63 (staging row)
  const int tk   = (t & 3) * 8;       // staging k-offset (elems)
  const int wid  = t >> 6, lane = t & 63;
  const int wm = wid >> 1, wn = wid & 1;
  const int lr = lane & 15;
  const int lkB = ((lane >> 4) * 8) * 2;   // byte offset of lane's k-slice

  char* ldsA = (char*)As + wid * 1024;     // wave-uniform bases
  char* ldsB = (char*)Bs + wid * 1024;

  f32x4 acc[4][4] = {};

  for (int k0 = 0; k0 < C_; k0 += BK) {
    const __bf16* ga = A  + (size_t)(row0 + trow) * C_ + k0 + tk;
    const __bf16* gb = Bm + (size_t)(col0 + trow) * C_ + k0 + tk;
    gload16(ga,           ldsA);
    gload16(ga + 64 * C_, ldsA + 4096);
    gload16(gb,           ldsB);
    gload16(gb + 64 * C_, ldsB + 4096);
    __syncthreads();   // compiler emits vmcnt(0) drain before barrier

    bf16x8 av[4], bv[4];
    #pragma unroll
    for (int m = 0; m < 4; ++m) {
      int row = wm * 64 + m * 16 + lr;
      av[m] = *(const bf16x8*)((const char*)As + row * 64 + lkB);
    }
    #pragma unroll
    for (int n = 0; n < 4; ++n) {
      int row = wn * 64 + n * 16 + lr;
      bv[n] = *(const bf16x8*)((const char*)Bs + row * 64 + lkB);
    }
    #pragma unroll
    for (int m = 0; m < 4; ++m)
      #pragma unroll
      for (int n = 0; n < 4; ++n)
        acc[m][n] = __builtin_amdgcn_mfma_f32_16x16x32_bf16(av[m], bv[n], acc[m][n], 0, 0, 0);
    __syncthreads();
  }

  // epilogue: C/D map col=lane&15, row=(lane>>4)*4+reg  [m89-verified]
  #pragma unroll
  for (int n = 0; n < 4; ++n) {
    int col = col0 + wn * 64 + n * 16 + lr;
    float bias = bb[b * C_ + col];
    #pragma unroll
    for (int m = 0; m < 4; ++m) {
      int row = row0 + wm * 64 + m * 16 + ((lane >> 4) * 4);
      f32x4 v = acc[m][n];
      #pragma unroll
      for (int r = 0; r < 4; ++r)
        O[(size_t)(row + r) * C_ + col] = v[r] + bias;
    }
  }
}

// ---------------- launcher ----------------
extern "C" void kernel_launch(void* const* d_in, const int* in_sizes, int n_in,
                              void* d_out, int out_size, void* d_ws, size_t ws_size,
                              hipStream_t stream) {
  const float* x    = (const float*)d_in[0];
  const float* x_ir = (const float*)d_in[1];
  const float* We   = (const float*)d_in[2];
  const float* be   = (const float*)d_in[3];
  const float* gw1  = (const float*)d_in[4];
  const float* gb1  = (const float*)d_in[5];
  const float* gw2  = (const float*)d_in[6];
  const float* gb2  = (const float*)d_in[7];
  float* out = (float*)d_out;

  char* ws = (char*)d_ws;
  __bf16* Wb  = (__bf16*)(ws + WB_OFF);
  __bf16* Xb  = (__bf16*)(ws + XB_OFF);             // [2][4][2048][1024]
  float*  gx  = (float*)(ws + GX_OFF);
  float*  g   = (float*)(ws + G_OFF);
  float*  bbp = (float*)(ws + BB_OFF);
  float*  h   = (float*)(ws + H_OFF);

  // gx accumulated via atomics -> zero it
  hipMemsetAsync(gx, 0, B_ * C_ * sizeof(float), stream);

  // casts: 8.4M elems each, 8/thread
  cast_kernel<<<4096, 256, 0, stream>>>(x,    Xb);
  cast_kernel<<<4096, 256, 0, stream>>>(x_ir, Xb + (size_t)B_ * N_ * C_);

  mean_kernel<<<dim3(32, 4, 4), 256, 0, stream>>>(x, gx);
  h_kernel<<<8, 256, 0, stream>>>(gx, gw1, gb1, h);
  gate2_kernel<<<1, 512, 0, stream>>>(h, gw2, gb2, g);
  bb_kernel<<<16, 256, 0, stream>>>(g, be, bbp);
  wb_kernel<<<4096, 256, 0, stream>>>(g, We, Wb);

  moe_gemm<<<dim3(C_ / BN, N_ / BM, 8), 256, 0, stream>>>(Xb, Wb, bbp, out);
}

// Round 2
// 115.676 us; speedup vs baseline: 1.1860x; 1.1860x over previous
//
#include <hip/hip_runtime.h>
#include <hip/hip_bf16.h>
#include <stdint.h>

// ---------------- problem constants ----------------
#define B_  4
#define N_  2048
#define C_  1024
#define E_  8
#define H_  512      // C/2

typedef __bf16 bf16x8 __attribute__((ext_vector_type(8)));
typedef __bf16 bf16x4 __attribute__((ext_vector_type(4)));
typedef float  f32x4  __attribute__((ext_vector_type(4)));

// ---------------- workspace layout (bytes) ----------------
#define WB_OFF   0ull
#define XB_OFF   (8ull*1024*1024)
#define GX_OFF   (XB_OFF + 32ull*1024*1024)
#define G_OFF    (GX_OFF + 4096ull*4)
#define BB_OFF   (G_OFF + 128ull)
#define H_OFF    (BB_OFF + 4096ull*4)

__device__ __forceinline__ void gload16(const void* g, void* l) {
  __builtin_amdgcn_global_load_lds((const __attribute__((address_space(1))) void*)g,
                                   (__attribute__((address_space(3))) void*)l, 16, 0, 0);
}

// ---------------- 1. f32 -> bf16 cast ----------------
__global__ void cast_kernel(const float* __restrict__ src, __bf16* __restrict__ dst) {
  size_t i = (size_t)blockIdx.x * blockDim.x + threadIdx.x;
  const float4* s = (const float4*)src + i * 2;
  float4 a = s[0], b = s[1];
  bf16x8 o;
  o[0] = (__bf16)a.x; o[1] = (__bf16)a.y; o[2] = (__bf16)a.z; o[3] = (__bf16)a.w;
  o[4] = (__bf16)b.x; o[5] = (__bf16)b.y; o[6] = (__bf16)b.z; o[7] = (__bf16)b.w;
  *(bf16x8*)(dst + i * 8) = o;
}

// ---------------- 2. gx = mean over N ----------------
__global__ void mean_kernel(const float* __restrict__ x, float* __restrict__ gx) {
  int b = blockIdx.z, cs = blockIdx.y, ns = blockIdx.x;
  int c = cs * 256 + threadIdx.x;
  const float* p = x + ((size_t)b * N_ + (size_t)ns * 64) * C_ + c;
  float s = 0.f;
  #pragma unroll 8
  for (int n = 0; n < 64; ++n) s += p[(size_t)n * C_];
  atomicAdd(&gx[b * C_ + c], s * (1.0f / N_));
}

// ---------------- 3. h = relu(gx @ gw1^T + gb1) ----------------
__global__ void h_kernel(const float* __restrict__ gx, const float* __restrict__ gw1,
                         const float* __restrict__ gb1, float* __restrict__ h) {
  __shared__ float sgx[B_][C_];
  int t = threadIdx.x;
  for (int i = t; i < B_ * C_; i += 256) sgx[i >> 10][i & 1023] = gx[i];
  __syncthreads();
  int j = blockIdx.x * 64 + (t >> 2);
  int b = t & 3;
  const float4* row = (const float4*)(gw1 + (size_t)j * C_);
  float acc = 0.f;
  #pragma unroll 4
  for (int c4 = 0; c4 < C_ / 4; ++c4) {
    float4 w = row[c4];
    acc += w.x * sgx[b][c4*4+0] + w.y * sgx[b][c4*4+1]
         + w.z * sgx[b][c4*4+2] + w.w * sgx[b][c4*4+3];
  }
  h[b * H_ + j] = fmaxf(acc + gb1[j], 0.f);
}

// ---------------- 4. logits + softmax -> g ----------------
__global__ __launch_bounds__(512) void gate2_kernel(const float* __restrict__ h,
    const float* __restrict__ gw2, const float* __restrict__ gb2, float* __restrict__ g) {
  __shared__ float slog[B_ * E_];
  int t = threadIdx.x, wv = t >> 6, lane = t & 63;
  for (int q = 0; q < 4; ++q) {
    int pi = wv * 4 + q;
    int b = pi >> 3, e = pi & 7;
    float s = 0.f;
    for (int k = lane; k < H_; k += 64) s += h[b * H_ + k] * gw2[e * H_ + k];
    for (int off = 32; off; off >>= 1) s += __shfl_down(s, off);
    if (lane == 0) slog[pi] = s + gb2[e];
  }
  __syncthreads();
  if (t < B_) {
    float m = -1e30f;
    for (int e = 0; e < E_; ++e) m = fmaxf(m, slog[t * E_ + e]);
    float p[E_], sum = 0.f;
    for (int e = 0; e < E_; ++e) { p[e] = __expf(slog[t * E_ + e] - m); sum += p[e]; }
    float inv = 1.f / sum;
    for (int e = 0; e < E_; ++e) g[t * E_ + e] = p[e] * inv;
  }
}

// ---------------- 5. bb = g @ be ----------------
__global__ void bb_kernel(const float* __restrict__ g, const float* __restrict__ be,
                          float* __restrict__ bb) {
  int i = blockIdx.x * 256 + threadIdx.x;
  int b = i >> 10, o = i & 1023;
  float s = 0.f;
  #pragma unroll
  for (int e = 0; e < E_; ++e) s += g[b * E_ + e] * be[e * C_ + o];
  bb[i] = s;
}

// ---------------- 6. Wb[b] = sum_e g[b,e]*We[e] (bf16) ----------------
__global__ void wb_kernel(const float* __restrict__ g, const float* __restrict__ We,
                          __bf16* __restrict__ Wb) {
  size_t i = (size_t)blockIdx.x * 256 + threadIdx.x;
  int b = (int)(i >> 18);
  size_t oc4 = i & ((1u << 18) - 1);
  float gl[E_];
  #pragma unroll
  for (int e = 0; e < E_; ++e) gl[e] = g[b * E_ + e];
  const float4* src = (const float4*)We + oc4;
  float4 acc = make_float4(0.f, 0.f, 0.f, 0.f);
  #pragma unroll
  for (int e = 0; e < E_; ++e) {
    float4 w = src[(size_t)e * (C_ * C_ / 4)];
    acc.x += gl[e] * w.x; acc.y += gl[e] * w.y;
    acc.z += gl[e] * w.z; acc.w += gl[e] * w.w;
  }
  bf16x4 o;
  o[0] = (__bf16)acc.x; o[1] = (__bf16)acc.y; o[2] = (__bf16)acc.z; o[3] = (__bf16)acc.w;
  *(bf16x4*)(Wb + i * 4) = o;
}

// ---------------- 7. batched GEMM: out = Xb @ Wb^T + bb ----------------
// 256x256 tile, BK=64, 8 waves (2Mx4N), 8-phase counted-vmcnt schedule,
// T2 XOR swizzle (linear gload_lds dest + pre-swizzled global src).
#define NT 16   // K / 64

__global__ __launch_bounds__(512, 2) void moe_gemm(const __bf16* __restrict__ Xb,
    const __bf16* __restrict__ Wb, const float* __restrict__ bb, float* __restrict__ out) {
  // [buf][ A: 256 rows x 128B | B: 256 cols x 128B ]
  __shared__ __attribute__((aligned(128))) char smem[2][65536];

  const int t = threadIdx.x;
  const int wid = t >> 6, lane = t & 63;
  const int wm = wid >> 2, wn = wid & 3;

  // XCD swizzle: dispatch index f -> XCD f%8 (round-robin); group one z per XCD
  int f = blockIdx.x;
  int swz = (f & 7) * 32 + (f >> 3);
  int xb_ = swz & 3, yb_ = (swz >> 2) & 7, z = swz >> 5;
  int b = z & 3;
  const size_t mat = (size_t)N_ * C_;
  const __bf16* A  = Xb + (size_t)z * mat;
  const __bf16* Bm = Wb + (size_t)b * C_ * C_;
  float* O = out + (size_t)z * mat;
  const int row0 = yb_ * 256, col0 = xb_ * 256;

  // staging lane constants: unit = 8 rows x 8 slots x 16B; row&7 == lane>>3
  const int lrow8 = lane >> 3;
  const int kblk  = ((lane & 7) ^ lrow8) << 3;      // pre-swizzled k-elem offset

  // ds-read lane constants: row&7 == lane&7 for all fragment rows
  const int lr = lane & 15;
  const int swzk0 = (((lane >> 4) + 0) ^ (lane & 7)) << 4;
  const int swzk1 = (((lane >> 4) + 4) ^ (lane & 7)) << 4;

  // stage unit sid: 0=A-lo(rows {0-63,128-191}), 1=B-lo(cols {0-31,64-95,...}),
  //                 2=B-hi(+32), 3=A-hi(+64)   [issue order == phase order]
  auto stage = [&](int sid, int k0, char* buf) {
    #pragma unroll
    for (int j = 0; j < 2; ++j) {
      int u = wid * 2 + j;
      int rl0 = u * 8;
      if (sid == 0 || sid == 3) {           // A
        int hh = (sid == 3) ? 1 : 0;
        int row_u = rl0 + (rl0 & 64) + hh * 64;
        const __bf16* src = A + (size_t)(row0 + row_u + lrow8) * C_ + k0 + kblk;
        gload16(src, buf + row_u * 128);
      } else {                              // B
        int hh = (sid == 2) ? 1 : 0;
        int col_u = (rl0 & 31) + (rl0 >> 5) * 64 + hh * 32;
        const __bf16* src = Bm + (size_t)(col0 + col_u + lrow8) * C_ + k0 + kblk;
        gload16(src, buf + 32768 + col_u * 128);
      }
    }
  };

  f32x4 acc[8][4] = {};
  bf16x8 av[4][2];        // current A quadrant (reused 2 phases)
  bf16x8 bv[2][2][2];     // [Bq][nq][ks], both col-groups held

  // prologue: stage all 4 units of tile 0 into buf0; wait units 0,1
  #pragma unroll
  for (int sid = 0; sid < 4; ++sid) stage(sid, 0, smem[0]);
  asm volatile("s_waitcnt vmcnt(4)" ::: "memory");
  __builtin_amdgcn_s_barrier();

  for (int kt = 0; kt < NT; ++kt) {
    char* rb = smem[kt & 1];
    char* wb = smem[(kt + 1) & 1];
    const char* rbA = rb;
    const char* rbB = rb + 32768;
    const bool more = (kt + 1 < NT);
    const int knext = (kt + 1) * 64;

    // phases: p0:(A0,B0) p1:(A0,B1) p2:(A1,B0) p3:(A1,B1); Aq=p>>1, Bq=p&1
    #pragma unroll
    for (int p = 0; p < 4; ++p) {
      const int Aq = p >> 1, Bq = p & 1;
      // --- ds-read new operands for this phase ---
      if (p == 0 || p == 2) {               // A quadrant Aq
        #pragma unroll
        for (int mq = 0; mq < 4; ++mq) {
          int rby = (wm * 128 + Aq * 64 + mq * 16 + lr) * 128;
          av[mq][0] = *(const bf16x8*)(rbA + rby + swzk0);
          av[mq][1] = *(const bf16x8*)(rbA + rby + swzk1);
        }
      }
      if (p == 0 || p == 1) {               // B col-group Bq (=p)
        #pragma unroll
        for (int nq = 0; nq < 2; ++nq) {
          int cby = (wn * 64 + Bq * 32 + nq * 16 + lr) * 128;
          bv[Bq][nq][0] = *(const bf16x8*)(rbB + cby + swzk0);
          bv[Bq][nq][1] = *(const bf16x8*)(rbB + cby + swzk1);
        }
      }
      // --- issue next-tile stage unit p ---
      if (more) stage(p, knext, wb);
      // --- wait own ds_reads, fence, MFMA cluster ---
      if (p < 3) {
        asm volatile("s_waitcnt lgkmcnt(0)" ::: "memory");
        __builtin_amdgcn_sched_barrier(0);
      }
      __builtin_amdgcn_s_setprio(1);
      #pragma unroll
      for (int mq = 0; mq < 4; ++mq)
        #pragma unroll
        for (int nq = 0; nq < 2; ++nq) {
          acc[Aq*4+mq][Bq*2+nq] = __builtin_amdgcn_mfma_f32_16x16x32_bf16(
              av[mq][0], bv[Bq][nq][0], acc[Aq*4+mq][Bq*2+nq], 0, 0, 0);
          acc[Aq*4+mq][Bq*2+nq] = __builtin_amdgcn_mfma_f32_16x16x32_bf16(
              av[mq][1], bv[Bq][nq][1], acc[Aq*4+mq][Bq*2+nq], 0, 0, 0);
        }
      __builtin_amdgcn_s_setprio(0);
      // --- counted vmcnt (FIFO: allow newest in-flight units), barrier ---
      if (more) {
        if (p == 2) asm volatile("s_waitcnt vmcnt(6)" ::: "memory");
        else        asm volatile("s_waitcnt vmcnt(4)" ::: "memory");
      } else {
        if (p == 0)      asm volatile("s_waitcnt vmcnt(2)" ::: "memory");
        else if (p == 1) asm volatile("s_waitcnt vmcnt(0)" ::: "memory");
      }
      __builtin_amdgcn_s_barrier();
    }
  }

  // epilogue: C/D map col=lane&15, row=(lane>>4)*4+reg
  #pragma unroll
  for (int n = 0; n < 4; ++n) {
    int col = col0 + wn * 64 + n * 16 + lr;
    float bias = bb[b * C_ + col];
    #pragma unroll
    for (int m = 0; m < 8; ++m) {
      int row = row0 + wm * 128 + m * 16 + ((lane >> 4) * 4);
      f32x4 v = acc[m][n];
      #pragma unroll
      for (int r = 0; r < 4; ++r)
        O[(size_t)(row + r) * C_ + col] = v[r] + bias;
    }
  }
}

// ---------------- launcher ----------------
extern "C" void kernel_launch(void* const* d_in, const int* in_sizes, int n_in,
                              void* d_out, int out_size, void* d_ws, size_t ws_size,
                              hipStream_t stream) {
  const float* x    = (const float*)d_in[0];
  const float* x_ir = (const float*)d_in[1];
  const float* We   = (const float*)d_in[2];
  const float* be   = (const float*)d_in[3];
  const float* gw1  = (const float*)d_in[4];
  const float* gb1  = (const float*)d_in[5];
  const float* gw2  = (const float*)d_in[6];
  const float* gb2  = (const float*)d_in[7];
  float* out = (float*)d_out;

  char* ws = (char*)d_ws;
  __bf16* Wb  = (__bf16*)(ws + WB_OFF);
  __bf16* Xb  = (__bf16*)(ws + XB_OFF);
  float*  gx  = (float*)(ws + GX_OFF);
  float*  g   = (float*)(ws + G_OFF);
  float*  bbp = (float*)(ws + BB_OFF);
  float*  h   = (float*)(ws + H_OFF);

  hipMemsetAsync(gx, 0, B_ * C_ * sizeof(float), stream);

  cast_kernel<<<4096, 256, 0, stream>>>(x,    Xb);
  cast_kernel<<<4096, 256, 0, stream>>>(x_ir, Xb + (size_t)B_ * N_ * C_);

  mean_kernel<<<dim3(32, 4, 4), 256, 0, stream>>>(x, gx);
  h_kernel<<<8, 256, 0, stream>>>(gx, gw1, gb1, h);
  gate2_kernel<<<1, 512, 0, stream>>>(h, gw2, gb2, g);
  bb_kernel<<<16, 256, 0, stream>>>(g, be, bbp);
  wb_kernel<<<4096, 256, 0, stream>>>(g, We, Wb);

  moe_gemm<<<256, 512, 0, stream>>>(Xb, Wb, bbp, out);
}

// Round 3
// 111.796 us; speedup vs baseline: 1.2271x; 1.0347x over previous
//
#include <hip/hip_runtime.h>
#include <hip/hip_bf16.h>
#include <stdint.h>

// ---------------- problem constants ----------------
#define B_  4
#define N_  2048
#define C_  1024
#define E_  8
#define H_  512      // C/2

typedef __bf16 bf16x8 __attribute__((ext_vector_type(8)));
typedef __bf16 bf16x4 __attribute__((ext_vector_type(4)));
typedef float  f32x4  __attribute__((ext_vector_type(4)));

// ---------------- workspace layout (bytes) ----------------
#define WB_OFF   0ull
#define XB_OFF   (8ull*1024*1024)
#define GX_OFF   (XB_OFF + 32ull*1024*1024)
#define G_OFF    (GX_OFF + 4096ull*4)
#define BB_OFF   (G_OFF + 128ull)
#define H_OFF    (BB_OFF + 4096ull*4)

__device__ __forceinline__ void gload16(const void* g, void* l) {
  __builtin_amdgcn_global_load_lds((const __attribute__((address_space(1))) void*)g,
                                   (__attribute__((address_space(3))) void*)l, 16, 0, 0);
}

// ---------------- 1. f32 -> bf16 cast, both inputs in one launch ----------------
__global__ void cast2_kernel(const float* __restrict__ x, const float* __restrict__ x_ir,
                             __bf16* __restrict__ dst) {
  size_t i = (size_t)blockIdx.x * 256 + threadIdx.x;      // one per 8 elems, grid 8192
  const size_t half = (size_t)B_ * N_ * C_ / 8;           // 1,048,576
  const float* src = (i < half) ? x : x_ir;
  size_t li = (i < half) ? i : i - half;
  const float4* s = (const float4*)src + li * 2;
  float4 a = s[0], b = s[1];
  bf16x8 o;
  o[0] = (__bf16)a.x; o[1] = (__bf16)a.y; o[2] = (__bf16)a.z; o[3] = (__bf16)a.w;
  o[4] = (__bf16)b.x; o[5] = (__bf16)b.y; o[6] = (__bf16)b.z; o[7] = (__bf16)b.w;
  *(bf16x8*)(dst + i * 8) = o;
}

// ---------------- 2. gx = mean over N ----------------
__global__ void mean_kernel(const float* __restrict__ x, float* __restrict__ gx) {
  int b = blockIdx.z, cs = blockIdx.y, ns = blockIdx.x;
  int c = cs * 256 + threadIdx.x;
  const float* p = x + ((size_t)b * N_ + (size_t)ns * 64) * C_ + c;
  float s = 0.f;
  #pragma unroll 8
  for (int n = 0; n < 64; ++n) s += p[(size_t)n * C_];
  atomicAdd(&gx[b * C_ + c], s * (1.0f / N_));
}

// ---------------- 3. h = relu(gx @ gw1^T + gb1) ----------------
__global__ void h_kernel(const float* __restrict__ gx, const float* __restrict__ gw1,
                         const float* __restrict__ gb1, float* __restrict__ h) {
  __shared__ float sgx[B_][C_];
  int t = threadIdx.x;
  for (int i = t; i < B_ * C_; i += 256) sgx[i >> 10][i & 1023] = gx[i];
  __syncthreads();
  int j = blockIdx.x * 64 + (t >> 2);
  int b = t & 3;
  const float4* row = (const float4*)(gw1 + (size_t)j * C_);
  float acc = 0.f;
  #pragma unroll 4
  for (int c4 = 0; c4 < C_ / 4; ++c4) {
    float4 w = row[c4];
    acc += w.x * sgx[b][c4*4+0] + w.y * sgx[b][c4*4+1]
         + w.z * sgx[b][c4*4+2] + w.w * sgx[b][c4*4+3];
  }
  h[b * H_ + j] = fmaxf(acc + gb1[j], 0.f);
}

// ---------------- 4. logits + softmax -> g, plus bb = g @ be ----------------
__global__ __launch_bounds__(512) void gate2_kernel(const float* __restrict__ h,
    const float* __restrict__ gw2, const float* __restrict__ gb2,
    const float* __restrict__ be, float* __restrict__ g, float* __restrict__ bbp) {
  __shared__ float slog[B_ * E_];
  __shared__ float sg[B_ * E_];
  int t = threadIdx.x, wv = t >> 6, lane = t & 63;
  for (int q = 0; q < 4; ++q) {
    int pi = wv * 4 + q;
    int b = pi >> 3, e = pi & 7;
    float s = 0.f;
    for (int k = lane; k < H_; k += 64) s += h[b * H_ + k] * gw2[e * H_ + k];
    for (int off = 32; off; off >>= 1) s += __shfl_down(s, off);
    if (lane == 0) slog[pi] = s + gb2[e];
  }
  __syncthreads();
  if (t < B_) {
    float m = -1e30f;
    for (int e = 0; e < E_; ++e) m = fmaxf(m, slog[t * E_ + e]);
    float p[E_], sum = 0.f;
    for (int e = 0; e < E_; ++e) { p[e] = __expf(slog[t * E_ + e] - m); sum += p[e]; }
    float inv = 1.f / sum;
    for (int e = 0; e < E_; ++e) { sg[t * E_ + e] = p[e] * inv; g[t * E_ + e] = p[e] * inv; }
  }
  __syncthreads();
  // bb: 4096 outputs, 8 per thread, coalesced in o
  #pragma unroll
  for (int q = 0; q < 8; ++q) {
    int i = q * 512 + t;
    int b = i >> 10, o = i & 1023;
    float s = 0.f;
    #pragma unroll
    for (int e = 0; e < E_; ++e) s += sg[b * E_ + e] * be[e * C_ + o];
    bbp[i] = s;
  }
}

// ---------------- 5. Wb[b] = sum_e g[b,e]*We[e] (bf16) ----------------
__global__ void wb_kernel(const float* __restrict__ g, const float* __restrict__ We,
                          __bf16* __restrict__ Wb) {
  size_t i = (size_t)blockIdx.x * 256 + threadIdx.x;
  int b = (int)(i >> 18);
  size_t oc4 = i & ((1u << 18) - 1);
  float gl[E_];
  #pragma unroll
  for (int e = 0; e < E_; ++e) gl[e] = g[b * E_ + e];
  const float4* src = (const float4*)We + oc4;
  float4 acc = make_float4(0.f, 0.f, 0.f, 0.f);
  #pragma unroll
  for (int e = 0; e < E_; ++e) {
    float4 w = src[(size_t)e * (C_ * C_ / 4)];
    acc.x += gl[e] * w.x; acc.y += gl[e] * w.y;
    acc.z += gl[e] * w.z; acc.w += gl[e] * w.w;
  }
  bf16x4 o;
  o[0] = (__bf16)acc.x; o[1] = (__bf16)acc.y; o[2] = (__bf16)acc.z; o[3] = (__bf16)acc.w;
  *(bf16x4*)(Wb + i * 4) = o;
}

// ---------------- 6. batched GEMM: out = Xb @ Wb^T + bb ----------------
// 256x256 tile, BK=64, 8 waves (2Mx4N), 8-phase counted-vmcnt schedule,
// T2 XOR swizzle, coalesced epilogue via per-wave LDS transpose.
#define NT 16   // K / 64

__global__ __launch_bounds__(512, 2) void moe_gemm(const __bf16* __restrict__ Xb,
    const __bf16* __restrict__ Wb, const float* __restrict__ bb, float* __restrict__ out) {
  __shared__ __attribute__((aligned(128))) char smem[2][65536];

  const int t = threadIdx.x;
  const int wid = t >> 6, lane = t & 63;
  const int wm = wid >> 2, wn = wid & 3;

  // XCD swizzle: one z-slice per XCD
  int f = blockIdx.x;
  int swz = (f & 7) * 32 + (f >> 3);
  int xb_ = swz & 3, yb_ = (swz >> 2) & 7, z = swz >> 5;
  int b = z & 3;
  const size_t mat = (size_t)N_ * C_;
  const __bf16* A  = Xb + (size_t)z * mat;
  const __bf16* Bm = Wb + (size_t)b * C_ * C_;
  float* O = out + (size_t)z * mat;
  const int row0 = yb_ * 256, col0 = xb_ * 256;

  // staging lane constants (pre-swizzled global src, linear LDS dest)
  const int lrow8 = lane >> 3;
  const int kblk  = ((lane & 7) ^ lrow8) << 3;

  // ds-read lane constants
  const int lr = lane & 15;
  const int swzk0 = (((lane >> 4) + 0) ^ (lane & 7)) << 4;
  const int swzk1 = (((lane >> 4) + 4) ^ (lane & 7)) << 4;

  auto stage = [&](int sid, int k0, char* buf) {
    #pragma unroll
    for (int j = 0; j < 2; ++j) {
      int u = wid * 2 + j;
      int rl0 = u * 8;
      if (sid == 0 || sid == 3) {           // A
        int hh = (sid == 3) ? 1 : 0;
        int row_u = rl0 + (rl0 & 64) + hh * 64;
        const __bf16* src = A + (size_t)(row0 + row_u + lrow8) * C_ + k0 + kblk;
        gload16(src, buf + row_u * 128);
      } else {                              // B
        int hh = (sid == 2) ? 1 : 0;
        int col_u = (rl0 & 31) + (rl0 >> 5) * 64 + hh * 32;
        const __bf16* src = Bm + (size_t)(col0 + col_u + lrow8) * C_ + k0 + kblk;
        gload16(src, buf + 32768 + col_u * 128);
      }
    }
  };

  f32x4 acc[8][4] = {};
  bf16x8 av[4][2];
  bf16x8 bv[2][2][2];

  #pragma unroll
  for (int sid = 0; sid < 4; ++sid) stage(sid, 0, smem[0]);
  asm volatile("s_waitcnt vmcnt(4)" ::: "memory");
  __builtin_amdgcn_s_barrier();

  for (int kt = 0; kt < NT; ++kt) {
    char* rb = smem[kt & 1];
    char* wbuf = smem[(kt + 1) & 1];
    const char* rbA = rb;
    const char* rbB = rb + 32768;
    const bool more = (kt + 1 < NT);
    const int knext = (kt + 1) * 64;

    #pragma unroll
    for (int p = 0; p < 4; ++p) {
      const int Aq = p >> 1, Bq = p & 1;
      if (p == 0 || p == 2) {
        #pragma unroll
        for (int mq = 0; mq < 4; ++mq) {
          int rby = (wm * 128 + Aq * 64 + mq * 16 + lr) * 128;
          av[mq][0] = *(const bf16x8*)(rbA + rby + swzk0);
          av[mq][1] = *(const bf16x8*)(rbA + rby + swzk1);
        }
      }
      if (p == 0 || p == 1) {
        #pragma unroll
        for (int nq = 0; nq < 2; ++nq) {
          int cby = (wn * 64 + Bq * 32 + nq * 16 + lr) * 128;
          bv[Bq][nq][0] = *(const bf16x8*)(rbB + cby + swzk0);
          bv[Bq][nq][1] = *(const bf16x8*)(rbB + cby + swzk1);
        }
      }
      if (more) stage(p, knext, wbuf);
      if (p < 3) {
        asm volatile("s_waitcnt lgkmcnt(0)" ::: "memory");
        __builtin_amdgcn_sched_barrier(0);
      }
      __builtin_amdgcn_s_setprio(1);
      #pragma unroll
      for (int mq = 0; mq < 4; ++mq)
        #pragma unroll
        for (int nq = 0; nq < 2; ++nq) {
          acc[Aq*4+mq][Bq*2+nq] = __builtin_amdgcn_mfma_f32_16x16x32_bf16(
              av[mq][0], bv[Bq][nq][0], acc[Aq*4+mq][Bq*2+nq], 0, 0, 0);
          acc[Aq*4+mq][Bq*2+nq] = __builtin_amdgcn_mfma_f32_16x16x32_bf16(
              av[mq][1], bv[Bq][nq][1], acc[Aq*4+mq][Bq*2+nq], 0, 0, 0);
        }
      __builtin_amdgcn_s_setprio(0);
      if (more) {
        if (p == 2) asm volatile("s_waitcnt vmcnt(6)" ::: "memory");
        else        asm volatile("s_waitcnt vmcnt(4)" ::: "memory");
      } else {
        if (p == 0)      asm volatile("s_waitcnt vmcnt(2)" ::: "memory");
        else if (p == 1) asm volatile("s_waitcnt vmcnt(0)" ::: "memory");
      }
      __builtin_amdgcn_s_barrier();
    }
  }

  // ---- coalesced epilogue: per-wave LDS transpose (16 x 68 f32, 2-way banks) ----
  // C/D map col=lane&15, row=(lane>>4)*4+reg. Stage one 16x64 m-group at a time,
  // re-read as row-major float4 -> 256B contiguous segments per 16 lanes.
  float* eb = (float*)(smem[0]) + wid * (16 * 68);
  const int er = lane >> 4;          // 0..3
  const f32x4 bias4 = *(const f32x4*)(bb + b * C_ + col0 + wn * 64 + lr * 4);

  #pragma unroll
  for (int m = 0; m < 8; ++m) {
    #pragma unroll
    for (int n = 0; n < 4; ++n) {
      f32x4 v = acc[m][n];
      #pragma unroll
      for (int r = 0; r < 4; ++r)
        eb[(er * 4 + r) * 68 + n * 16 + lr] = v[r];
    }
    asm volatile("s_waitcnt lgkmcnt(0)" ::: "memory");
    __builtin_amdgcn_sched_barrier(0);
    #pragma unroll
    for (int j = 0; j < 4; ++j) {
      int row = j * 4 + er;
      f32x4 v = *(const f32x4*)(eb + row * 68 + lr * 4);
      v[0] += bias4[0]; v[1] += bias4[1]; v[2] += bias4[2]; v[3] += bias4[3];
      int grow = row0 + wm * 128 + m * 16 + row;
      int gcol = col0 + wn * 64 + lr * 4;
      *(f32x4*)(O + (size_t)grow * C_ + gcol) = v;
    }
  }
}

// ---------------- launcher ----------------
extern "C" void kernel_launch(void* const* d_in, const int* in_sizes, int n_in,
                              void* d_out, int out_size, void* d_ws, size_t ws_size,
                              hipStream_t stream) {
  const float* x    = (const float*)d_in[0];
  const float* x_ir = (const float*)d_in[1];
  const float* We   = (const float*)d_in[2];
  const float* be   = (const float*)d_in[3];
  const float* gw1  = (const float*)d_in[4];
  const float* gb1  = (const float*)d_in[5];
  const float* gw2  = (const float*)d_in[6];
  const float* gb2  = (const float*)d_in[7];
  float* out = (float*)d_out;

  char* ws = (char*)d_ws;
  __bf16* Wb  = (__bf16*)(ws + WB_OFF);
  __bf16* Xb  = (__bf16*)(ws + XB_OFF);
  float*  gx  = (float*)(ws + GX_OFF);
  float*  g   = (float*)(ws + G_OFF);
  float*  bbp = (float*)(ws + BB_OFF);
  float*  h   = (float*)(ws + H_OFF);

  hipMemsetAsync(gx, 0, B_ * C_ * sizeof(float), stream);

  cast2_kernel<<<8192, 256, 0, stream>>>(x, x_ir, Xb);
  mean_kernel<<<dim3(32, 4, 4), 256, 0, stream>>>(x, gx);
  h_kernel<<<8, 256, 0, stream>>>(gx, gw1, gb1, h);
  gate2_kernel<<<1, 512, 0, stream>>>(h, gw2, gb2, be, g, bbp);
  wb_kernel<<<4096, 256, 0, stream>>>(g, We, Wb);

  moe_gemm<<<256, 512, 0, stream>>>(Xb, Wb, bbp, out);
}